// Round 1
// baseline (761.022 us; speedup 1.0000x reference)
//
#include <hip/hip_runtime.h>
#include <math.h>

// Problem constants (fixed by reference setup_inputs)
#define BB    32      // batch
#define LL    4096    // tokens = 64*64
#define CC    768     // channels
#define NHH   12      // heads
#define DH    64      // head dim
#define NCH   32      // token chunks per batch (L / CHUNK)
#define CHUNK 128     // tokens per block (k1/k4)
#define TPW   32      // tokens per wave (CHUNK / 4 waves)
#define EPSL  1e-5f
#define SCALE 0.125f  // d^-0.5 = 64^-0.5

// ---------------------------------------------------------------------------
// k1: one streaming pass over x.
//  - per-token LayerNorm stats (mu, rstd) via full-wave butterfly reduction
//  - per-(b,chunk) channel partial sums (for the global average pool)
// Lane l of a wave owns channels c = 256*j + 4*l + k  (j=0..2, k=0..3),
// loaded as 3 coalesced float4s per token row.
// ---------------------------------------------------------------------------
__global__ __launch_bounds__(256) void k1_stats(const float* __restrict__ x,
                                                float* __restrict__ csum,
                                                float* __restrict__ muW,
                                                float* __restrict__ rsW) {
    int bid = blockIdx.x;
    int b = bid >> 5, chunk = bid & 31;
    int tid = threadIdx.x;
    int wave = tid >> 6, lane = tid & 63;

    float4 acc[3];
#pragma unroll
    for (int j = 0; j < 3; j++) acc[j] = make_float4(0.f, 0.f, 0.f, 0.f);

    const float* xb = x + (size_t)b * LL * CC;
    int t0 = chunk * CHUNK + wave * TPW;

    for (int tt = 0; tt < TPW; tt++) {
        int tok = t0 + tt;
        const float* row = xb + (size_t)tok * CC;
        float4 xv[3];
#pragma unroll
        for (int j = 0; j < 3; j++)
            xv[j] = *(const float4*)(row + j * 256 + lane * 4);

        float ts = 0.f, tq = 0.f;
#pragma unroll
        for (int j = 0; j < 3; j++) {
            ts += xv[j].x + xv[j].y + xv[j].z + xv[j].w;
            tq = fmaf(xv[j].x, xv[j].x, tq);
            tq = fmaf(xv[j].y, xv[j].y, tq);
            tq = fmaf(xv[j].z, xv[j].z, tq);
            tq = fmaf(xv[j].w, xv[j].w, tq);
            acc[j].x += xv[j].x;
            acc[j].y += xv[j].y;
            acc[j].z += xv[j].z;
            acc[j].w += xv[j].w;
        }
        // full 64-lane butterfly reduce (broadcasts result to all lanes)
#pragma unroll
        for (int mask = 32; mask >= 1; mask >>= 1) {
            ts += __shfl_xor(ts, mask, 64);
            tq += __shfl_xor(tq, mask, 64);
        }
        if (lane == 0) {
            float mu  = ts * (1.f / 768.f);
            float var = tq * (1.f / 768.f) - mu * mu;
            muW[(size_t)b * LL + tok] = mu;
            rsW[(size_t)b * LL + tok] = rsqrtf(var + EPSL);
        }
    }

    // combine the 4 waves' channel partials, write one 768-vector per block
    __shared__ float lds[4][768];
#pragma unroll
    for (int j = 0; j < 3; j++)
        *(float4*)&lds[wave][j * 256 + lane * 4] = acc[j];
    __syncthreads();
    float* cs = csum + (size_t)(b * NCH + chunk) * CC;
    for (int c = tid; c < CC; c += 256)
        cs[c] = lds[0][c] + lds[1][c] + lds[2][c] + lds[3][c];
}

// ---------------------------------------------------------------------------
// k2: per-b — reduce channel sums -> pooled mean, then q = mean@Wq + bq,
// store qs = q * SCALE. One block per b, 256 threads, 3 outputs/thread.
// ---------------------------------------------------------------------------
__global__ __launch_bounds__(256) void k2_q(const float* __restrict__ csum,
                                            const float* __restrict__ Wq,
                                            const float* __restrict__ bq,
                                            float* __restrict__ qs) {
    int b = blockIdx.x;
    int t = threadIdx.x;
    __shared__ float xm[768];
    for (int c = t; c < 768; c += 256) {
        float s = 0.f;
        for (int ch = 0; ch < NCH; ch++)
            s += csum[(size_t)(b * NCH + ch) * CC + c];
        xm[c] = s * (1.f / 4096.f);
    }
    __syncthreads();
    float a0 = bq[t], a1 = bq[t + 256], a2 = bq[t + 512];
    for (int cin = 0; cin < 768; cin++) {
        float xv = xm[cin];
        const float* wr = Wq + (size_t)cin * 768;
        a0 = fmaf(xv, wr[t], a0);
        a1 = fmaf(xv, wr[t + 256], a1);
        a2 = fmaf(xv, wr[t + 512], a2);
    }
    float* q = qs + (size_t)b * 768;
    q[t]       = a0 * SCALE;
    q[t + 256] = a1 * SCALE;
    q[t + 512] = a2 * SCALE;
}

// ---------------------------------------------------------------------------
// k3: per-b — collapse the K projection:
//   wt[b,h,c] = sum_d Wk[c, h*64+d] * qs[b, h*64+d]
//   bt[b,h]   = sum_d bk[h*64+d]    * qs[b, h*64+d]
// ---------------------------------------------------------------------------
__global__ __launch_bounds__(256) void k3_wt(const float* __restrict__ qs,
                                             const float* __restrict__ Wk,
                                             const float* __restrict__ bk,
                                             float* __restrict__ wt,
                                             float* __restrict__ bt) {
    int b = blockIdx.x;
    int t = threadIdx.x;
    __shared__ float ql[768];
    for (int c = t; c < 768; c += 256) ql[c] = qs[(size_t)b * 768 + c];
    __syncthreads();
    const float4* q4 = (const float4*)ql;
    for (int cc = 0; cc < 3; cc++) {
        int c = t + cc * 256;
        const float4* wr = (const float4*)(Wk + (size_t)c * 768);
#pragma unroll
        for (int h = 0; h < 12; h++) {
            float a = 0.f;
#pragma unroll 4
            for (int d4 = 0; d4 < 16; d4++) {
                float4 w = wr[h * 16 + d4];
                float4 q = q4[h * 16 + d4];
                a = fmaf(w.x, q.x, fmaf(w.y, q.y, fmaf(w.z, q.z, fmaf(w.w, q.w, a))));
            }
            wt[(size_t)(b * 12 + h) * 768 + c] = a;
        }
    }
    if (t < 12) {
        float s = 0.f;
        for (int d = 0; d < 64; d++) s += bk[t * 64 + d] * ql[t * 64 + d];
        bt[b * 12 + t] = s;
    }
}

// ---------------------------------------------------------------------------
// k4: main fused pass. Per (b, chunk-of-128-tokens) block, 4 waves x 32 tokens.
// Lane l owns channels c = 256*j + 4*l + k; channel c belongs to head
// h = 4*j + (l>>4), head-dim d = 4*(l&15)+k. So a 16-lane xor-butterfly
// (width 16) reduces each head's 64-channel dot product, landing z[h] in
// exactly the lanes whose kv values feed that head's o-accumulator.
// Flash-style online softmax per head; per-chunk partials (m,s,o[64]) out.
// ---------------------------------------------------------------------------
__global__ __launch_bounds__(256) void k4_main(const float* __restrict__ x,
                                               const float* __restrict__ gamma,
                                               const float* __restrict__ beta,
                                               const float* __restrict__ muW,
                                               const float* __restrict__ rsW,
                                               const float* __restrict__ wt,
                                               const float* __restrict__ bt,
                                               float* __restrict__ pm,
                                               float* __restrict__ ps,
                                               float* __restrict__ po) {
    int bid = blockIdx.x;
    int b = bid >> 5, chunk = bid & 31;
    int tid = threadIdx.x;
    int wave = tid >> 6, lane = tid & 63;
    int seg = lane >> 4, l15 = lane & 15;

    float4 g[3], be[3], w4[3];
    float btl[3];
    int hj[3];
#pragma unroll
    for (int j = 0; j < 3; j++) {
        int c = j * 256 + lane * 4;
        hj[j] = 4 * j + seg;
        g[j]  = *(const float4*)(gamma + c);
        be[j] = *(const float4*)(beta + c);
        w4[j] = *(const float4*)(wt + (size_t)(b * 12 + hj[j]) * 768 + c);
        btl[j] = bt[b * 12 + hj[j]];
    }

    float m[3], s[3];
    float4 o[3];
#pragma unroll
    for (int j = 0; j < 3; j++) {
        m[j] = -INFINITY;
        s[j] = 0.f;
        o[j] = make_float4(0.f, 0.f, 0.f, 0.f);
    }

    const float* xb  = x + (size_t)b * LL * CC;
    const float* mub = muW + (size_t)b * LL;
    const float* rsb = rsW + (size_t)b * LL;
    int t0 = chunk * CHUNK + wave * TPW;

    for (int tt = 0; tt < TPW; tt++) {
        int tok = t0 + tt;
        const float* row = xb + (size_t)tok * CC;
        float4 xv[3];
#pragma unroll
        for (int j = 0; j < 3; j++)
            xv[j] = *(const float4*)(row + j * 256 + lane * 4);
        float mu = mub[tok], rs = rsb[tok];

        float4 kv[3];
        float pp[3];
#pragma unroll
        for (int j = 0; j < 3; j++) {
            kv[j].x = fmaf((xv[j].x - mu) * rs, g[j].x, be[j].x);
            kv[j].y = fmaf((xv[j].y - mu) * rs, g[j].y, be[j].y);
            kv[j].z = fmaf((xv[j].z - mu) * rs, g[j].z, be[j].z);
            kv[j].w = fmaf((xv[j].w - mu) * rs, g[j].w, be[j].w);
            pp[j] = fmaf(kv[j].x, w4[j].x,
                    fmaf(kv[j].y, w4[j].y,
                    fmaf(kv[j].z, w4[j].z, kv[j].w * w4[j].w)));
        }
        // 16-lane segmented butterfly: full head dot product, broadcast in segment
#pragma unroll
        for (int mask = 1; mask < 16; mask <<= 1) {
#pragma unroll
            for (int j = 0; j < 3; j++)
                pp[j] += __shfl_xor(pp[j], mask, 16);
        }
#pragma unroll
        for (int j = 0; j < 3; j++) {
            float z  = pp[j] + btl[j];
            float mn = fmaxf(m[j], z);
            float al = __expf(m[j] - mn);   // m=-inf first iter -> exp(-inf)=0
            float p  = __expf(z - mn);
            s[j] = fmaf(s[j], al, p);
            o[j].x = fmaf(o[j].x, al, p * kv[j].x);
            o[j].y = fmaf(o[j].y, al, p * kv[j].y);
            o[j].z = fmaf(o[j].z, al, p * kv[j].z);
            o[j].w = fmaf(o[j].w, al, p * kv[j].w);
            m[j] = mn;
        }
    }

    // merge 4 waves -> one chunk partial per (b,chunk,h)
    __shared__ float lm[4][12], lsd[4][12];
    __shared__ float lo[4][12][64];
    if (l15 == 0) {
#pragma unroll
        for (int j = 0; j < 3; j++) {
            lm[wave][hj[j]]  = m[j];
            lsd[wave][hj[j]] = s[j];
        }
    }
#pragma unroll
    for (int j = 0; j < 3; j++)
        *(float4*)&lo[wave][hj[j]][4 * l15] = o[j];
    __syncthreads();

    size_t base = (size_t)(b * NCH + chunk) * 12;
    for (int r = tid; r < 768; r += 256) {
        int hh = r >> 6, dd = r & 63;
        float mM = fmaxf(fmaxf(lm[0][hh], lm[1][hh]), fmaxf(lm[2][hh], lm[3][hh]));
        float ss = 0.f, oo = 0.f;
#pragma unroll
        for (int w = 0; w < 4; w++) {
            float e = __expf(lm[w][hh] - mM);
            ss = fmaf(lsd[w][hh], e, ss);
            oo = fmaf(lo[w][hh][dd], e, oo);
        }
        po[(base + hh) * 64 + dd] = oo;
        if (dd == 0) {
            pm[base + hh] = mM;
            ps[base + hh] = ss;
        }
    }
}

// ---------------------------------------------------------------------------
// k5: merge the 32 chunk partials per (b,h) -> final output [B, C].
// ---------------------------------------------------------------------------
__global__ __launch_bounds__(64) void k5_out(const float* __restrict__ pm,
                                             const float* __restrict__ ps,
                                             const float* __restrict__ po,
                                             float* __restrict__ out) {
    int blk = blockIdx.x;
    int b = blk / 12, hh = blk % 12;
    int dd = threadIdx.x;
    float mM = -INFINITY;
    for (int ch = 0; ch < NCH; ch++)
        mM = fmaxf(mM, pm[(size_t)(b * NCH + ch) * 12 + hh]);
    float ss = 0.f, oo = 0.f;
    for (int ch = 0; ch < NCH; ch++) {
        size_t idx = (size_t)(b * NCH + ch) * 12 + hh;
        float e = __expf(pm[idx] - mM);
        ss = fmaf(ps[idx], e, ss);
        oo = fmaf(po[idx * 64 + dd], e, oo);
    }
    out[(size_t)b * 768 + hh * 64 + dd] = oo / ss;
}

extern "C" void kernel_launch(void* const* d_in, const int* in_sizes, int n_in,
                              void* d_out, int out_size, void* d_ws, size_t ws_size,
                              hipStream_t stream) {
    const float* x     = (const float*)d_in[0];
    const float* gamma = (const float*)d_in[1];
    const float* beta  = (const float*)d_in[2];
    const float* Wq    = (const float*)d_in[3];
    const float* bq    = (const float*)d_in[4];
    const float* Wk    = (const float*)d_in[5];
    const float* bk    = (const float*)d_in[6];
    float* out = (float*)d_out;

    // workspace layout (floats) — total ~2.18M floats = 8.7 MB
    float* ws   = (float*)d_ws;
    float* csum = ws;              // B*NCH*C   = 786432
    float* muW  = csum + 786432;   // B*L       = 131072
    float* rsW  = muW + 131072;    // B*L       = 131072
    float* qs   = rsW + 131072;    // B*C       = 24576
    float* wt   = qs + 24576;      // B*12*C    = 294912
    float* bt   = wt + 294912;     // B*12      = 384
    float* pm   = bt + 384;        // B*NCH*12  = 12288
    float* ps   = pm + 12288;      // B*NCH*12  = 12288
    float* po   = ps + 12288;      // B*NCH*12*64 = 786432

    hipLaunchKernelGGL(k1_stats, dim3(BB * NCH), dim3(256), 0, stream, x, csum, muW, rsW);
    hipLaunchKernelGGL(k2_q,     dim3(BB),       dim3(256), 0, stream, csum, Wq, bq, qs);
    hipLaunchKernelGGL(k3_wt,    dim3(BB),       dim3(256), 0, stream, qs, Wk, bk, wt, bt);
    hipLaunchKernelGGL(k4_main,  dim3(BB * NCH), dim3(256), 0, stream,
                       x, gamma, beta, muW, rsW, wt, bt, pm, ps, po);
    hipLaunchKernelGGL(k5_out,   dim3(BB * NHH), dim3(64),  0, stream, pm, ps, po, out);
}

// Round 2
// 670.711 us; speedup vs baseline: 1.1346x; 1.1346x over previous
//
#include <hip/hip_runtime.h>
#include <math.h>

// Problem constants (fixed by reference setup_inputs)
#define BB    32      // batch
#define LL    4096    // tokens = 64*64
#define CC    768     // channels
#define NHH   12      // heads
#define DH    64      // head dim
#define NCH   32      // token chunks per batch (L / CHUNK)
#define CHUNK 128     // tokens per block (k1/k4)
#define TPW   32      // tokens per wave (CHUNK / 4 waves)
#define EPSL  1e-5f
#define SCALE 0.125f  // d^-0.5 = 64^-0.5

// ---------------------------------------------------------------------------
// k1: one streaming pass over x.  (unchanged from round 1 — bit-identical)
//  - per-token LayerNorm stats (mu, rstd) via full-wave butterfly reduction
//  - per-(b,chunk) channel partial sums (for the global average pool)
// ---------------------------------------------------------------------------
__global__ __launch_bounds__(256) void k1_stats(const float* __restrict__ x,
                                                float* __restrict__ csum,
                                                float* __restrict__ muW,
                                                float* __restrict__ rsW) {
    int bid = blockIdx.x;
    int b = bid >> 5, chunk = bid & 31;
    int tid = threadIdx.x;
    int wave = tid >> 6, lane = tid & 63;

    float4 acc[3];
#pragma unroll
    for (int j = 0; j < 3; j++) acc[j] = make_float4(0.f, 0.f, 0.f, 0.f);

    const float* xb = x + (size_t)b * LL * CC;
    int t0 = chunk * CHUNK + wave * TPW;

    for (int tt = 0; tt < TPW; tt++) {
        int tok = t0 + tt;
        const float* row = xb + (size_t)tok * CC;
        float4 xv[3];
#pragma unroll
        for (int j = 0; j < 3; j++)
            xv[j] = *(const float4*)(row + j * 256 + lane * 4);

        float ts = 0.f, tq = 0.f;
#pragma unroll
        for (int j = 0; j < 3; j++) {
            ts += xv[j].x + xv[j].y + xv[j].z + xv[j].w;
            tq = fmaf(xv[j].x, xv[j].x, tq);
            tq = fmaf(xv[j].y, xv[j].y, tq);
            tq = fmaf(xv[j].z, xv[j].z, tq);
            tq = fmaf(xv[j].w, xv[j].w, tq);
            acc[j].x += xv[j].x;
            acc[j].y += xv[j].y;
            acc[j].z += xv[j].z;
            acc[j].w += xv[j].w;
        }
#pragma unroll
        for (int mask = 32; mask >= 1; mask >>= 1) {
            ts += __shfl_xor(ts, mask, 64);
            tq += __shfl_xor(tq, mask, 64);
        }
        if (lane == 0) {
            float mu  = ts * (1.f / 768.f);
            float var = tq * (1.f / 768.f) - mu * mu;
            muW[(size_t)b * LL + tok] = mu;
            rsW[(size_t)b * LL + tok] = rsqrtf(var + EPSL);
        }
    }

    __shared__ float lds[4][768];
#pragma unroll
    for (int j = 0; j < 3; j++)
        *(float4*)&lds[wave][j * 256 + lane * 4] = acc[j];
    __syncthreads();
    float* cs = csum + (size_t)(b * NCH + chunk) * CC;
    for (int c = tid; c < CC; c += 256)
        cs[c] = lds[0][c] + lds[1][c] + lds[2][c] + lds[3][c];
}

// ---------------------------------------------------------------------------
// k2: partial pooled-matvec. Grid (32 b, 4 cin-slices) — 128 blocks instead
// of 32, 192-iteration loops instead of 768, to cover L2 load latency.
//   qpart[b,g,c] = sum_{cin in slice g} mean[cin] * Wq[cin,c]
// ---------------------------------------------------------------------------
__global__ __launch_bounds__(256) void k2_qpart(const float* __restrict__ csum,
                                                const float* __restrict__ Wq,
                                                float* __restrict__ qpart) {
    int b = blockIdx.x, g = blockIdx.y;
    int t = threadIdx.x;
    __shared__ float xm[192];
    if (t < 192) {
        int cc = g * 192 + t;
        float s = 0.f;
        for (int ch = 0; ch < NCH; ch++)
            s += csum[(size_t)(b * NCH + ch) * CC + cc];
        xm[t] = s * (1.f / 4096.f);
    }
    __syncthreads();
    float a0 = 0.f, a1 = 0.f, a2 = 0.f;
#pragma unroll 4
    for (int i = 0; i < 192; i++) {
        int cin = g * 192 + i;
        float xv = xm[i];
        const float* wr = Wq + (size_t)cin * 768;
        a0 = fmaf(xv, wr[t], a0);
        a1 = fmaf(xv, wr[t + 256], a1);
        a2 = fmaf(xv, wr[t + 512], a2);
    }
    float* qp = qpart + (size_t)(b * 4 + g) * 768;
    qp[t]       = a0;
    qp[t + 256] = a1;
    qp[t + 512] = a2;
}

// ---------------------------------------------------------------------------
// k3: collapse the K projection. Grid (32 b, 3 c-slices) — 96 blocks.
// Each block first combines the 4 qpart slices + bq, applies SCALE (cheap,
// redundant across the 3 slice-blocks), then:
//   wt[b,h,c] = sum_d Wk[c, h*64+d] * qs[b, h*64+d]
//   bt[b,h]   = sum_d bk[h*64+d]    * qs[b, h*64+d]
// ---------------------------------------------------------------------------
__global__ __launch_bounds__(256) void k3_wt(const float* __restrict__ qpart,
                                             const float* __restrict__ bq,
                                             const float* __restrict__ Wk,
                                             const float* __restrict__ bk,
                                             float* __restrict__ wt,
                                             float* __restrict__ bt) {
    int b = blockIdx.x, cc = blockIdx.y;
    int t = threadIdx.x;
    __shared__ float ql[768];
    const float* qp = qpart + (size_t)b * 4 * 768;
    for (int c = t; c < 768; c += 256) {
        float q = ((qp[c] + qp[768 + c]) + qp[2 * 768 + c]) + qp[3 * 768 + c] + bq[c];
        ql[c] = q * SCALE;
    }
    __syncthreads();
    const float4* q4 = (const float4*)ql;
    int c = t + cc * 256;
    const float4* wr = (const float4*)(Wk + (size_t)c * 768);
#pragma unroll
    for (int h = 0; h < 12; h++) {
        float a = 0.f;
#pragma unroll 4
        for (int d4 = 0; d4 < 16; d4++) {
            float4 w = wr[h * 16 + d4];
            float4 q = q4[h * 16 + d4];
            a = fmaf(w.x, q.x, fmaf(w.y, q.y, fmaf(w.z, q.z, fmaf(w.w, q.w, a))));
        }
        wt[(size_t)(b * 12 + h) * 768 + c] = a;
    }
    if (cc == 0 && t < 12) {
        float s = 0.f;
        for (int d = 0; d < 64; d++) s += bk[t * 64 + d] * ql[t * 64 + d];
        bt[b * 12 + t] = s;
    }
}

// ---------------------------------------------------------------------------
// k4: main fused pass.  (unchanged from round 1 — bit-identical)
// ---------------------------------------------------------------------------
__global__ __launch_bounds__(256) void k4_main(const float* __restrict__ x,
                                               const float* __restrict__ gamma,
                                               const float* __restrict__ beta,
                                               const float* __restrict__ muW,
                                               const float* __restrict__ rsW,
                                               const float* __restrict__ wt,
                                               const float* __restrict__ bt,
                                               float* __restrict__ pm,
                                               float* __restrict__ ps,
                                               float* __restrict__ po) {
    int bid = blockIdx.x;
    int b = bid >> 5, chunk = bid & 31;
    int tid = threadIdx.x;
    int wave = tid >> 6, lane = tid & 63;
    int seg = lane >> 4, l15 = lane & 15;

    float4 g[3], be[3], w4[3];
    float btl[3];
    int hj[3];
#pragma unroll
    for (int j = 0; j < 3; j++) {
        int c = j * 256 + lane * 4;
        hj[j] = 4 * j + seg;
        g[j]  = *(const float4*)(gamma + c);
        be[j] = *(const float4*)(beta + c);
        w4[j] = *(const float4*)(wt + (size_t)(b * 12 + hj[j]) * 768 + c);
        btl[j] = bt[b * 12 + hj[j]];
    }

    float m[3], s[3];
    float4 o[3];
#pragma unroll
    for (int j = 0; j < 3; j++) {
        m[j] = -INFINITY;
        s[j] = 0.f;
        o[j] = make_float4(0.f, 0.f, 0.f, 0.f);
    }

    const float* xb  = x + (size_t)b * LL * CC;
    const float* mub = muW + (size_t)b * LL;
    const float* rsb = rsW + (size_t)b * LL;
    int t0 = chunk * CHUNK + wave * TPW;

    for (int tt = 0; tt < TPW; tt++) {
        int tok = t0 + tt;
        const float* row = xb + (size_t)tok * CC;
        float4 xv[3];
#pragma unroll
        for (int j = 0; j < 3; j++)
            xv[j] = *(const float4*)(row + j * 256 + lane * 4);
        float mu = mub[tok], rs = rsb[tok];

        float4 kv[3];
        float pp[3];
#pragma unroll
        for (int j = 0; j < 3; j++) {
            kv[j].x = fmaf((xv[j].x - mu) * rs, g[j].x, be[j].x);
            kv[j].y = fmaf((xv[j].y - mu) * rs, g[j].y, be[j].y);
            kv[j].z = fmaf((xv[j].z - mu) * rs, g[j].z, be[j].z);
            kv[j].w = fmaf((xv[j].w - mu) * rs, g[j].w, be[j].w);
            pp[j] = fmaf(kv[j].x, w4[j].x,
                    fmaf(kv[j].y, w4[j].y,
                    fmaf(kv[j].z, w4[j].z, kv[j].w * w4[j].w)));
        }
#pragma unroll
        for (int mask = 1; mask < 16; mask <<= 1) {
#pragma unroll
            for (int j = 0; j < 3; j++)
                pp[j] += __shfl_xor(pp[j], mask, 16);
        }
#pragma unroll
        for (int j = 0; j < 3; j++) {
            float z  = pp[j] + btl[j];
            float mn = fmaxf(m[j], z);
            float al = __expf(m[j] - mn);
            float p  = __expf(z - mn);
            s[j] = fmaf(s[j], al, p);
            o[j].x = fmaf(o[j].x, al, p * kv[j].x);
            o[j].y = fmaf(o[j].y, al, p * kv[j].y);
            o[j].z = fmaf(o[j].z, al, p * kv[j].z);
            o[j].w = fmaf(o[j].w, al, p * kv[j].w);
            m[j] = mn;
        }
    }

    __shared__ float lm[4][12], lsd[4][12];
    __shared__ float lo[4][12][64];
    if (l15 == 0) {
#pragma unroll
        for (int j = 0; j < 3; j++) {
            lm[wave][hj[j]]  = m[j];
            lsd[wave][hj[j]] = s[j];
        }
    }
#pragma unroll
    for (int j = 0; j < 3; j++)
        *(float4*)&lo[wave][hj[j]][4 * l15] = o[j];
    __syncthreads();

    size_t base = (size_t)(b * NCH + chunk) * 12;
    for (int r = tid; r < 768; r += 256) {
        int hh = r >> 6, dd = r & 63;
        float mM = fmaxf(fmaxf(lm[0][hh], lm[1][hh]), fmaxf(lm[2][hh], lm[3][hh]));
        float ss = 0.f, oo = 0.f;
#pragma unroll
        for (int w = 0; w < 4; w++) {
            float e = __expf(lm[w][hh] - mM);
            ss = fmaf(lsd[w][hh], e, ss);
            oo = fmaf(lo[w][hh][dd], e, oo);
        }
        po[(base + hh) * 64 + dd] = oo;
        if (dd == 0) {
            pm[base + hh] = mM;
            ps[base + hh] = ss;
        }
    }
}

// ---------------------------------------------------------------------------
// k5: merge the 32 chunk partials per (b,h).  (unchanged from round 1)
// ---------------------------------------------------------------------------
__global__ __launch_bounds__(64) void k5_out(const float* __restrict__ pm,
                                             const float* __restrict__ ps,
                                             const float* __restrict__ po,
                                             float* __restrict__ out) {
    int blk = blockIdx.x;
    int b = blk / 12, hh = blk % 12;
    int dd = threadIdx.x;
    float mM = -INFINITY;
    for (int ch = 0; ch < NCH; ch++)
        mM = fmaxf(mM, pm[(size_t)(b * NCH + ch) * 12 + hh]);
    float ss = 0.f, oo = 0.f;
    for (int ch = 0; ch < NCH; ch++) {
        size_t idx = (size_t)(b * NCH + ch) * 12 + hh;
        float e = __expf(pm[idx] - mM);
        ss = fmaf(ps[idx], e, ss);
        oo = fmaf(po[idx * 64 + dd], e, oo);
    }
    out[(size_t)b * 768 + hh * 64 + dd] = oo / ss;
}

extern "C" void kernel_launch(void* const* d_in, const int* in_sizes, int n_in,
                              void* d_out, int out_size, void* d_ws, size_t ws_size,
                              hipStream_t stream) {
    const float* x     = (const float*)d_in[0];
    const float* gamma = (const float*)d_in[1];
    const float* beta  = (const float*)d_in[2];
    const float* Wq    = (const float*)d_in[3];
    const float* bq    = (const float*)d_in[4];
    const float* Wk    = (const float*)d_in[5];
    const float* bk    = (const float*)d_in[6];
    float* out = (float*)d_out;

    // workspace layout (floats) — total ~2.3M floats = 9.1 MB
    float* ws    = (float*)d_ws;
    float* csum  = ws;               // B*NCH*C     = 786432
    float* muW   = csum + 786432;    // B*L         = 131072
    float* rsW   = muW + 131072;     // B*L         = 131072
    float* qpart = rsW + 131072;     // B*4*C       = 98304
    float* wt    = qpart + 98304;    // B*12*C      = 294912
    float* bt    = wt + 294912;      // B*12        = 384
    float* pm    = bt + 384;         // B*NCH*12    = 12288
    float* ps    = pm + 12288;       // B*NCH*12    = 12288
    float* po    = ps + 12288;       // B*NCH*12*64 = 786432

    hipLaunchKernelGGL(k1_stats, dim3(BB * NCH), dim3(256), 0, stream, x, csum, muW, rsW);
    hipLaunchKernelGGL(k2_qpart, dim3(BB, 4),    dim3(256), 0, stream, csum, Wq, qpart);
    hipLaunchKernelGGL(k3_wt,    dim3(BB, 3),    dim3(256), 0, stream, qpart, bq, Wk, bk, wt, bt);
    hipLaunchKernelGGL(k4_main,  dim3(BB * NCH), dim3(256), 0, stream,
                       x, gamma, beta, muW, rsW, wt, bt, pm, ps, po);
    hipLaunchKernelGGL(k5_out,   dim3(BB * NHH), dim3(64),  0, stream, pm, ps, po, out);
}